// Round 3
// baseline (2148.405 us; speedup 1.0000x reference)
//
#include <hip/hip_runtime.h>

typedef unsigned short u16;
typedef unsigned int u32;
typedef __bf16 bf16x8 __attribute__((ext_vector_type(8)));
typedef float f32x4 __attribute__((ext_vector_type(4)));

__device__ __forceinline__ float bf2f(u16 u) {
    union { u32 u; float f; } x; x.u = ((u32)u) << 16; return x.f;
}
__device__ __forceinline__ u16 f2bf(float f) {
    union { float f; u32 u; } x; x.f = f;
    u32 r = x.u + 0x7fffu + ((x.u >> 16) & 1u);
    return (u16)(r >> 16);
}
__device__ __forceinline__ void unpack8(uint4 d, float* f) {
    f[0] = bf2f((u16)(d.x & 0xffffu)); f[1] = bf2f((u16)(d.x >> 16));
    f[2] = bf2f((u16)(d.y & 0xffffu)); f[3] = bf2f((u16)(d.y >> 16));
    f[4] = bf2f((u16)(d.z & 0xffffu)); f[5] = bf2f((u16)(d.z >> 16));
    f[6] = bf2f((u16)(d.w & 0xffffu)); f[7] = bf2f((u16)(d.w >> 16));
}

// ---- dtype sniffing: fp32 data read as bf16 halfwords has wild exponents ----
__global__ __launch_bounds__(256) void k_flag(const void* __restrict__ x, int* __restrict__ flag) {
    const u16* p = (const u16*)x;
    const int t = threadIdx.x;
    float mx = 0.f;
    for (int i = t; i < 4096; i += 256) {
        float v = fabsf(bf2f(p[i]));
        if (!(v < 1e30f)) v = 1e30f;  // NaN/Inf -> big
        mx = fmaxf(mx, v);
    }
    __shared__ float red[256];
    red[t] = mx; __syncthreads();
    for (int s = 128; s > 0; s >>= 1) {
        if (t < s) red[t] = fmaxf(red[t], red[t + s]);
        __syncthreads();
    }
    if (t == 0) *flag = (red[0] > 1e6f) ? 1 : 0;  // 1 = fp32, 0 = bf16
}

// ---------------- weight transpose+convert: Wt[n*K+k] = bf16(W[k*N+n]) ----------------
__global__ void k_tr(const void* __restrict__ W, u16* __restrict__ Wt, int K, int N,
                     const int* __restrict__ flagp) {
    const int flag = *flagp;
    int idx = blockIdx.x * 256 + threadIdx.x;
    if (idx < K * N) {
        int k = idx / N, n = idx - k * N;
        u16 v = flag ? f2bf(((const float*)W)[idx]) : ((const u16*)W)[idx];
        Wt[n * K + k] = v;
    }
}

// ---------------- LayerNorm over D=256, one wave per local row ----------------
// in_row = (r>>7)*so + (r&127)*si + base;  out row r dense bf16.
// xmode: 1 -> x has flag dtype; 0 -> x is always bf16 (internal buffer).
__global__ __launch_bounds__(256) void k_ln(
        const void* __restrict__ x, const void* __restrict__ g,
        const void* __restrict__ b, u16* __restrict__ xn,
        int so, int si, int base, const int* __restrict__ flagp, int xmode) {
    const int flag = *flagp;
    const int xf = xmode ? flag : 0;
    const int wave = threadIdx.x >> 6, lane = threadIdx.x & 63;
    const int r = blockIdx.x * 4 + wave;
    const int in_row = (r >> 7) * so + (r & 127) * si + base;
    const size_t off = (size_t)in_row * 256 + lane * 4;
    float v[4];
    if (xf) {
        float4 d = *(const float4*)((const float*)x + off);
        v[0] = d.x; v[1] = d.y; v[2] = d.z; v[3] = d.w;
    } else {
        uint2 d = *(const uint2*)((const u16*)x + off);
        v[0] = bf2f((u16)(d.x & 0xffffu)); v[1] = bf2f((u16)(d.x >> 16));
        v[2] = bf2f((u16)(d.y & 0xffffu)); v[3] = bf2f((u16)(d.y >> 16));
    }
    float s = v[0] + v[1] + v[2] + v[3];
    #pragma unroll
    for (int o2 = 32; o2 > 0; o2 >>= 1) s += __shfl_xor(s, o2, 64);
    float mu = s * (1.f / 256.f);
    float vs = 0.f;
    #pragma unroll
    for (int e = 0; e < 4; e++) { float t = v[e] - mu; vs += t * t; }
    #pragma unroll
    for (int o2 = 32; o2 > 0; o2 >>= 1) vs += __shfl_xor(vs, o2, 64);
    float rr = rsqrtf(vs * (1.f / 256.f) + 1e-5f);
    float gf[4], bf_[4];
    if (flag) {
        float4 gg = *(const float4*)((const float*)g + lane * 4);
        float4 bb = *(const float4*)((const float*)b + lane * 4);
        gf[0] = gg.x; gf[1] = gg.y; gf[2] = gg.z; gf[3] = gg.w;
        bf_[0] = bb.x; bf_[1] = bb.y; bf_[2] = bb.z; bf_[3] = bb.w;
    } else {
        uint2 gg = *(const uint2*)((const u16*)g + lane * 4);
        uint2 bb = *(const uint2*)((const u16*)b + lane * 4);
        gf[0] = bf2f((u16)(gg.x & 0xffffu)); gf[1] = bf2f((u16)(gg.x >> 16));
        gf[2] = bf2f((u16)(gg.y & 0xffffu)); gf[3] = bf2f((u16)(gg.y >> 16));
        bf_[0] = bf2f((u16)(bb.x & 0xffffu)); bf_[1] = bf2f((u16)(bb.x >> 16));
        bf_[2] = bf2f((u16)(bb.y & 0xffffu)); bf_[3] = bf2f((u16)(bb.y >> 16));
    }
    u16 o[4];
    #pragma unroll
    for (int e = 0; e < 4; e++) o[e] = f2bf((v[e] - mu) * rr * gf[e] + bf_[e]);
    uint2 ov;
    ov.x = (u32)o[0] | ((u32)o[1] << 16);
    ov.y = (u32)o[2] | ((u32)o[3] << 16);
    *(uint2*)(xn + (size_t)r * 256 + lane * 4) = ov;
}

// ------------- pairwise bias: bias[h][i][j] = sum_d pw[i][j][d]*we[d][h] -------------
__global__ __launch_bounds__(256) void k_bias(
        const void* __restrict__ pw, const void* __restrict__ we,
        float* __restrict__ bias, const int* __restrict__ flagp) {
    const int flag = *flagp;
    __shared__ float swe[2048];  // [256][8] fp32
    for (int t = threadIdx.x; t < 2048; t += 256)
        swe[t] = flag ? ((const float*)we)[t] : bf2f(((const u16*)we)[t]);
    __syncthreads();
    const int i = blockIdx.x, j = threadIdx.x;
    const size_t rowoff = ((size_t)i * 256 + j) * 256;
    float acc[8] = {0.f, 0.f, 0.f, 0.f, 0.f, 0.f, 0.f, 0.f};
    for (int d0 = 0; d0 < 256; d0 += 8) {
        float f[8];
        if (flag) {
            const float* p32 = (const float*)pw + rowoff + d0;
            float4 a = *(const float4*)p32;
            float4 b = *(const float4*)(p32 + 4);
            f[0] = a.x; f[1] = a.y; f[2] = a.z; f[3] = a.w;
            f[4] = b.x; f[5] = b.y; f[6] = b.z; f[7] = b.w;
        } else {
            unpack8(*(const uint4*)((const u16*)pw + rowoff + d0), f);
        }
        #pragma unroll
        for (int e = 0; e < 8; e++) {
            const float* w = swe + (d0 + e) * 8;
            #pragma unroll
            for (int hh = 0; hh < 8; hh++) acc[hh] += f[e] * w[hh];
        }
    }
    #pragma unroll
    for (int hh = 0; hh < 8; hh++)
        bias[((size_t)hh * 256 + i) * 256 + j] = acc[hh];
}

// ---------------- MFMA GEMM: C[M,N] = A[M,256] @ Bt[N,256]^T ----------------
// 128x128 tile, 4 waves of 64x64, 16x16x32 bf16 MFMA.
// EPI: v += bias[col](flag dtype) + res[res_off + orow*N+col].
// RESF: res has flag dtype, else always bf16. OUTF: store flag dtype, else bf16.
// PERM: orow = (row&127)*256 + n0 + (row>>7), else orow = row.
template<bool EPI, bool PERM, bool RESF, bool OUTF>
__global__ __launch_bounds__(256, 2) void k_gemm(
        const u16* __restrict__ A, const u16* __restrict__ Bt, void* __restrict__ C,
        size_t c_off, int N, const void* __restrict__ bias,
        const void* __restrict__ res, size_t res_off, int n0,
        const int* __restrict__ flagp) {
    constexpr int K = 256;
    const int flag = *flagp;
    __shared__ u16 sA[128 * 40];
    __shared__ u16 sB[128 * 40];
    const int tid = threadIdx.x;
    const int bm = blockIdx.x * 128, bn = blockIdx.y * 128;
    const int wave = tid >> 6, lane = tid & 63;
    const int wm = (wave >> 1) * 64, wn = (wave & 1) * 64;
    const int lr = lane & 15, lq = lane >> 4;
    f32x4 acc[4][4];
    #pragma unroll
    for (int a = 0; a < 4; a++)
        #pragma unroll
        for (int b2 = 0; b2 < 4; b2++) {
            acc[a][b2][0] = 0.f; acc[a][b2][1] = 0.f;
            acc[a][b2][2] = 0.f; acc[a][b2][3] = 0.f;
        }
    for (int k0 = 0; k0 < K; k0 += 32) {
        for (int c = tid; c < 512; c += 256) {
            int r = c >> 2, cc = (c & 3) << 3;
            *(uint4*)(sA + r * 40 + cc) = *(const uint4*)(A + (size_t)(bm + r) * K + k0 + cc);
            *(uint4*)(sB + r * 40 + cc) = *(const uint4*)(Bt + (size_t)(bn + r) * K + k0 + cc);
        }
        __syncthreads();
        bf16x8 af[4], bfr[4];
        #pragma unroll
        for (int t = 0; t < 4; t++) {
            af[t]  = *(const bf16x8*)(sA + (wm + t * 16 + lr) * 40 + lq * 8);
            bfr[t] = *(const bf16x8*)(sB + (wn + t * 16 + lr) * 40 + lq * 8);
        }
        #pragma unroll
        for (int mt = 0; mt < 4; mt++)
            #pragma unroll
            for (int nt = 0; nt < 4; nt++)
                acc[mt][nt] = __builtin_amdgcn_mfma_f32_16x16x32_bf16(
                        af[mt], bfr[nt], acc[mt][nt], 0, 0, 0);
        __syncthreads();
    }
    #pragma unroll
    for (int mt = 0; mt < 4; mt++)
        #pragma unroll
        for (int nt = 0; nt < 4; nt++)
            #pragma unroll
            for (int r = 0; r < 4; r++) {
                int row = bm + wm + mt * 16 + lq * 4 + r;
                int orow = PERM ? ((row & 127) * 256 + n0 + (row >> 7)) : row;
                int col = bn + wn + nt * 16 + lr;
                float v = acc[mt][nt][r];
                if (EPI) {
                    float bv = flag ? ((const float*)bias)[col] : bf2f(((const u16*)bias)[col]);
                    size_t ri = res_off + (size_t)orow * N + col;
                    float rv = (RESF && flag) ? ((const float*)res)[ri]
                                              : bf2f(((const u16*)res)[ri]);
                    v += bv + rv;
                }
                size_t ci = c_off + (size_t)orow * N + col;
                if (OUTF && flag) ((float*)C)[ci] = v;
                else ((u16*)C)[ci] = f2bf(v);
            }
}

// ---------------- attention + output gating ----------------
// P: [rows][1024] bf16 = [q | k | v | g]. One block per (head, group). Thread i =
// query pos in group. rowi = i*istride + b*bstride; mask_idx = i*mi_s + b*mb_s + m_base.
template<bool HB, int L>
__global__ __launch_bounds__(256) void k_attn(
        const u16* __restrict__ P, const float* __restrict__ bias,
        const int* __restrict__ mask, const void* __restrict__ bg,
        u16* __restrict__ out, int istride, int bstride,
        int mi_s, int mb_s, int m_base, const int* __restrict__ flagp) {
    const int flag = *flagp;
    __shared__ float sk[L * 32];
    __shared__ u16   sv[L * 32];
    __shared__ float smk[L];
    const int h = blockIdx.x, b = blockIdx.y;
    const int i = threadIdx.x;
    const int rowi = i * istride + b * bstride;
    const u16* kp = P + (size_t)rowi * 1024 + 256 + h * 32;
    #pragma unroll
    for (int c = 0; c < 4; c++) {
        float kf[8];
        unpack8(*(const uint4*)(kp + c * 8), kf);
        *(float4*)(sk + i * 32 + c * 8)     = make_float4(kf[0], kf[1], kf[2], kf[3]);
        *(float4*)(sk + i * 32 + c * 8 + 4) = make_float4(kf[4], kf[5], kf[6], kf[7]);
        *(uint4*)(sv + i * 32 + c * 8) = *(const uint4*)(kp + 256 + c * 8);
    }
    const bool mi = mask[i * mi_s + b * mb_s + m_base] != 0;
    smk[i] = mi ? 1.f : 0.f;
    __syncthreads();

    float q[32];
    const u16* qp = P + (size_t)rowi * 1024 + h * 32;
    #pragma unroll
    for (int c = 0; c < 4; c++) unpack8(*(const uint4*)(qp + c * 8), q + c * 8);

    const float* bp = nullptr;
    if constexpr (HB) bp = bias + ((size_t)h * L + i) * L;

    float m = -1e30f, l = 0.f;
    float o[32];
    #pragma unroll
    for (int d = 0; d < 32; d++) o[d] = 0.f;

    for (int j = 0; j < L; j++) {
        const float* kj = sk + j * 32;
        float s = 0.f;
        #pragma unroll
        for (int d = 0; d < 32; d++) s += q[d] * kj[d];
        s *= 0.17677669529663687f;  // 1/sqrt(32)
        if constexpr (HB) s += bp[j];
        s = (mi && smk[j] > 0.f) ? s : -1e9f;
        float mn = fmaxf(m, s);
        float aexp = exp2f((m - mn) * 1.4426950408889634f);
        float p = exp2f((s - mn) * 1.4426950408889634f);
        l = l * aexp + p;
        const u16* vj = sv + j * 32;
        #pragma unroll
        for (int c = 0; c < 4; c++) {
            float vf[8];
            unpack8(*(const uint4*)(vj + c * 8), vf);
            #pragma unroll
            for (int e = 0; e < 8; e++)
                o[c * 8 + e] = o[c * 8 + e] * aexp + p * vf[e];
        }
        m = mn;
    }
    float inv = 1.f / l;
    const u16* gp = P + (size_t)rowi * 1024 + 768 + h * 32;
    u16* op = out + (size_t)rowi * 256 + h * 32;
    #pragma unroll
    for (int d = 0; d < 32; d++) {
        float bgv = flag ? ((const float*)bg)[h * 32 + d] : bf2f(((const u16*)bg)[h * 32 + d]);
        float g = bf2f(gp[d]) + bgv;
        float sig = 1.f / (1.f + exp2f(-g * 1.4426950408889634f));
        op[d] = f2bf(o[d] * inv * sig);
    }
}

extern "C" void kernel_launch(void* const* d_in, const int* in_sizes, int n_in,
                              void* d_out, int out_size, void* d_ws, size_t ws_size,
                              hipStream_t stream) {
    (void)in_sizes; (void)n_in; (void)out_size; (void)ws_size;
    const void* x        = d_in[0];
    const void* pw       = d_in[1];
    const int*  mask     = (const int*)d_in[2];
    const void* row_ln_g = d_in[3];
    const void* row_ln_b = d_in[4];
    const void* row_wq   = d_in[5];
    const void* row_wkv  = d_in[6];
    const void* row_wg   = d_in[7];
    const void* row_bg   = d_in[8];
    const void* row_wo   = d_in[9];
    const void* row_bo   = d_in[10];
    const void* row_we   = d_in[11];
    const void* col_ln_g = d_in[12];
    const void* col_ln_b = d_in[13];
    const void* col_wq   = d_in[14];
    const void* col_wkv  = d_in[15];
    const void* col_wg   = d_in[16];
    const void* col_bg   = d_in[17];
    const void* col_wo   = d_in[18];
    const void* col_bo   = d_in[19];

    // workspace layout (total ~30.6 MB)
    char* ws = (char*)d_ws;
    int*   flagp  = (int*)ws;                   // dtype flag
    u16*   Wt     = (u16*)(ws + 512);           // [1024][256] bf16
    u16*   WoT    = (u16*)(ws + 524800);        // [256][256] bf16
    float* biasb  = (float*)(ws + 655872);      // [8][256][256] fp32
    u16*   xn_c   = (u16*)(ws + 2753024);       // [4096][256] bf16
    u16*   attn_c = (u16*)(ws + 4850176);       // [4096][256] bf16
    u16*   P_c    = (u16*)(ws + 6947328);       // [4096][1024] bf16
    u16*   x1     = (u16*)(ws + 15335936);      // [32768][256] bf16

    k_flag<<<1, 256, 0, stream>>>(x, flagp);

    // ---------------- stage 1: row attention (x1 in ws, bf16) ----------------
    k_tr<<<256, 256, 0, stream>>>(row_wq,  Wt,             256, 256, flagp);
    k_tr<<<512, 256, 0, stream>>>(row_wkv, Wt + 256 * 256, 256, 512, flagp);
    k_tr<<<256, 256, 0, stream>>>(row_wg,  Wt + 768 * 256, 256, 256, flagp);
    k_tr<<<256, 256, 0, stream>>>(row_wo,  WoT,            256, 256, flagp);
    k_bias<<<256, 256, 0, stream>>>(pw, row_we, biasb, flagp);
    for (int c = 0; c < 8; c++) {
        const int s0 = c * 16;  // 16 sequences per chunk -> 4096 rows
        k_ln<<<1024, 256, 0, stream>>>(x, row_ln_g, row_ln_b, xn_c,
                                       128, 1, s0 * 256, flagp, 1);
        k_gemm<false, false, false, false><<<dim3(32, 8), 256, 0, stream>>>(
                xn_c, Wt, P_c, 0, 1024, nullptr, nullptr, 0, 0, flagp);
        k_attn<true, 256><<<dim3(8, 16), 256, 0, stream>>>(
                P_c, biasb, mask, row_bg, attn_c, 1, 256, 1, 256, s0 * 256, flagp);
        k_gemm<true, false, true, false><<<dim3(32, 2), 256, 0, stream>>>(
                attn_c, WoT, x1, (size_t)s0 * 65536, 256,
                row_bo, x, (size_t)s0 * 65536, 0, flagp);
    }

    // ---------------- stage 2: column attention (reads x1 bf16, writes d_out) ----------------
    k_tr<<<256, 256, 0, stream>>>(col_wq,  Wt,             256, 256, flagp);
    k_tr<<<512, 256, 0, stream>>>(col_wkv, Wt + 256 * 256, 256, 512, flagp);
    k_tr<<<256, 256, 0, stream>>>(col_wg,  Wt + 768 * 256, 256, 256, flagp);
    k_tr<<<256, 256, 0, stream>>>(col_wo,  WoT,            256, 256, flagp);
    for (int c = 0; c < 8; c++) {
        const int n0 = c * 32;  // 32 residue columns per chunk -> 4096 rows (n-major)
        k_ln<<<1024, 256, 0, stream>>>(x1, col_ln_g, col_ln_b, xn_c,
                                       1, 256, n0, flagp, 0);
        k_gemm<false, false, false, false><<<dim3(32, 8), 256, 0, stream>>>(
                xn_c, Wt, P_c, 0, 1024, nullptr, nullptr, 0, 0, flagp);
        k_attn<false, 128><<<dim3(8, 32), 128, 0, stream>>>(
                P_c, nullptr, mask, col_bg, attn_c, 1, 128, 256, 1, n0, flagp);
        k_gemm<true, true, false, true><<<dim3(32, 2), 256, 0, stream>>>(
                attn_c, WoT, d_out, 0, 256, col_bo, x1, 0, n0, flagp);
    }
}

// Round 4
// 818.862 us; speedup vs baseline: 2.6236x; 2.6236x over previous
//
#include <hip/hip_runtime.h>

typedef unsigned short u16;
typedef unsigned int u32;
typedef __bf16 bf16x8 __attribute__((ext_vector_type(8)));
typedef float f32x4 __attribute__((ext_vector_type(4)));

__device__ __forceinline__ float bf2f(u16 u) {
    union { u32 u; float f; } x; x.u = ((u32)u) << 16; return x.f;
}
__device__ __forceinline__ u16 f2bf(float f) {
    union { float f; u32 u; } x; x.f = f;
    u32 r = x.u + 0x7fffu + ((x.u >> 16) & 1u);
    return (u16)(r >> 16);
}
__device__ __forceinline__ void unpack8(uint4 d, float* f) {
    f[0] = bf2f((u16)(d.x & 0xffffu)); f[1] = bf2f((u16)(d.x >> 16));
    f[2] = bf2f((u16)(d.y & 0xffffu)); f[3] = bf2f((u16)(d.y >> 16));
    f[4] = bf2f((u16)(d.z & 0xffffu)); f[5] = bf2f((u16)(d.z >> 16));
    f[6] = bf2f((u16)(d.w & 0xffffu)); f[7] = bf2f((u16)(d.w >> 16));
}

// ---- dtype sniffing: fp32 data read as bf16 halfwords has wild exponents ----
__global__ __launch_bounds__(256) void k_flag(const void* __restrict__ x, int* __restrict__ flag) {
    const u16* p = (const u16*)x;
    const int t = threadIdx.x;
    float mx = 0.f;
    for (int i = t; i < 4096; i += 256) {
        float v = fabsf(bf2f(p[i]));
        if (!(v < 1e30f)) v = 1e30f;  // NaN/Inf -> big
        mx = fmaxf(mx, v);
    }
    __shared__ float red[256];
    red[t] = mx; __syncthreads();
    for (int s = 128; s > 0; s >>= 1) {
        if (t < s) red[t] = fmaxf(red[t], red[t + s]);
        __syncthreads();
    }
    if (t == 0) *flag = (red[0] > 1e6f) ? 1 : 0;  // 1 = fp32, 0 = bf16
}

// ---------------- weight transpose+convert: Wt[n*K+k] = bf16(W[k*N+n]) ----------------
__global__ void k_tr(const void* __restrict__ W, u16* __restrict__ Wt, int K, int N,
                     const int* __restrict__ flagp) {
    const int flag = *flagp;
    int idx = blockIdx.x * 256 + threadIdx.x;
    if (idx < K * N) {
        int k = idx / N, n = idx - k * N;
        u16 v = flag ? f2bf(((const float*)W)[idx]) : ((const u16*)W)[idx];
        Wt[n * K + k] = v;
    }
}

// ---------------- LayerNorm over D=256, one wave per local row ----------------
// in_row = (r>>7)*so + (r&127)*si + base;  out row r dense bf16.
// xmode: 1 -> x has flag dtype; 0 -> x is always bf16 (internal buffer).
__global__ __launch_bounds__(256) void k_ln(
        const void* __restrict__ x, const void* __restrict__ g,
        const void* __restrict__ b, u16* __restrict__ xn,
        int so, int si, int base, const int* __restrict__ flagp, int xmode) {
    const int flag = *flagp;
    const int xf = xmode ? flag : 0;
    const int wave = threadIdx.x >> 6, lane = threadIdx.x & 63;
    const int r = blockIdx.x * 4 + wave;
    const int in_row = (r >> 7) * so + (r & 127) * si + base;
    const size_t off = (size_t)in_row * 256 + lane * 4;
    float v[4];
    if (xf) {
        float4 d = *(const float4*)((const float*)x + off);
        v[0] = d.x; v[1] = d.y; v[2] = d.z; v[3] = d.w;
    } else {
        uint2 d = *(const uint2*)((const u16*)x + off);
        v[0] = bf2f((u16)(d.x & 0xffffu)); v[1] = bf2f((u16)(d.x >> 16));
        v[2] = bf2f((u16)(d.y & 0xffffu)); v[3] = bf2f((u16)(d.y >> 16));
    }
    float s = v[0] + v[1] + v[2] + v[3];
    #pragma unroll
    for (int o2 = 32; o2 > 0; o2 >>= 1) s += __shfl_xor(s, o2, 64);
    float mu = s * (1.f / 256.f);
    float vs = 0.f;
    #pragma unroll
    for (int e = 0; e < 4; e++) { float t = v[e] - mu; vs += t * t; }
    #pragma unroll
    for (int o2 = 32; o2 > 0; o2 >>= 1) vs += __shfl_xor(vs, o2, 64);
    float rr = rsqrtf(vs * (1.f / 256.f) + 1e-5f);
    float gf[4], bf_[4];
    if (flag) {
        float4 gg = *(const float4*)((const float*)g + lane * 4);
        float4 bb = *(const float4*)((const float*)b + lane * 4);
        gf[0] = gg.x; gf[1] = gg.y; gf[2] = gg.z; gf[3] = gg.w;
        bf_[0] = bb.x; bf_[1] = bb.y; bf_[2] = bb.z; bf_[3] = bb.w;
    } else {
        uint2 gg = *(const uint2*)((const u16*)g + lane * 4);
        uint2 bb = *(const uint2*)((const u16*)b + lane * 4);
        gf[0] = bf2f((u16)(gg.x & 0xffffu)); gf[1] = bf2f((u16)(gg.x >> 16));
        gf[2] = bf2f((u16)(gg.y & 0xffffu)); gf[3] = bf2f((u16)(gg.y >> 16));
        bf_[0] = bf2f((u16)(bb.x & 0xffffu)); bf_[1] = bf2f((u16)(bb.x >> 16));
        bf_[2] = bf2f((u16)(bb.y & 0xffffu)); bf_[3] = bf2f((u16)(bb.y >> 16));
    }
    u16 o[4];
    #pragma unroll
    for (int e = 0; e < 4; e++) o[e] = f2bf((v[e] - mu) * rr * gf[e] + bf_[e]);
    uint2 ov;
    ov.x = (u32)o[0] | ((u32)o[1] << 16);
    ov.y = (u32)o[2] | ((u32)o[3] << 16);
    *(uint2*)(xn + (size_t)r * 256 + lane * 4) = ov;
}

// ------------- pairwise bias: bias[h][i][j] = sum_d pw[i][j][d]*we[d][h] -------------
__global__ __launch_bounds__(256) void k_bias(
        const void* __restrict__ pw, const void* __restrict__ we,
        float* __restrict__ bias, const int* __restrict__ flagp) {
    const int flag = *flagp;
    __shared__ float swe[2048];  // [256][8] fp32
    for (int t = threadIdx.x; t < 2048; t += 256)
        swe[t] = flag ? ((const float*)we)[t] : bf2f(((const u16*)we)[t]);
    __syncthreads();
    const int i = blockIdx.x, j = threadIdx.x;
    const size_t rowoff = ((size_t)i * 256 + j) * 256;
    float acc[8] = {0.f, 0.f, 0.f, 0.f, 0.f, 0.f, 0.f, 0.f};
    for (int d0 = 0; d0 < 256; d0 += 8) {
        float f[8];
        if (flag) {
            const float* p32 = (const float*)pw + rowoff + d0;
            float4 a = *(const float4*)p32;
            float4 b = *(const float4*)(p32 + 4);
            f[0] = a.x; f[1] = a.y; f[2] = a.z; f[3] = a.w;
            f[4] = b.x; f[5] = b.y; f[6] = b.z; f[7] = b.w;
        } else {
            unpack8(*(const uint4*)((const u16*)pw + rowoff + d0), f);
        }
        #pragma unroll
        for (int e = 0; e < 8; e++) {
            const float* w = swe + (d0 + e) * 8;
            #pragma unroll
            for (int hh = 0; hh < 8; hh++) acc[hh] += f[e] * w[hh];
        }
    }
    #pragma unroll
    for (int hh = 0; hh < 8; hh++)
        bias[((size_t)hh * 256 + i) * 256 + j] = acc[hh];
}

// ---------------- MFMA GEMM: C[M,N] = A[M,256] @ Bt[N,256]^T ----------------
// 128x128 tile, 4 waves of 64x64, 16x16x32 bf16 MFMA.
// EPI: v += bias[col](flag dtype) + res[res_off + orow*N+col].
// RESF: res has flag dtype, else always bf16. OUTF: store flag dtype, else bf16.
// PERM: orow = (row&127)*256 + n0 + (row>>7), else orow = row.
template<bool EPI, bool PERM, bool RESF, bool OUTF>
__global__ __launch_bounds__(256, 2) void k_gemm(
        const u16* __restrict__ A, const u16* __restrict__ Bt, void* __restrict__ C,
        size_t c_off, int N, const void* __restrict__ bias,
        const void* __restrict__ res, size_t res_off, int n0,
        const int* __restrict__ flagp) {
    constexpr int K = 256;
    const int flag = *flagp;
    __shared__ u16 sA[128 * 40];
    __shared__ u16 sB[128 * 40];
    const int tid = threadIdx.x;
    const int bm = blockIdx.x * 128, bn = blockIdx.y * 128;
    const int wave = tid >> 6, lane = tid & 63;
    const int wm = (wave >> 1) * 64, wn = (wave & 1) * 64;
    const int lr = lane & 15, lq = lane >> 4;
    f32x4 acc[4][4];
    #pragma unroll
    for (int a = 0; a < 4; a++)
        #pragma unroll
        for (int b2 = 0; b2 < 4; b2++) {
            acc[a][b2][0] = 0.f; acc[a][b2][1] = 0.f;
            acc[a][b2][2] = 0.f; acc[a][b2][3] = 0.f;
        }
    for (int k0 = 0; k0 < K; k0 += 32) {
        for (int c = tid; c < 512; c += 256) {
            int r = c >> 2, cc = (c & 3) << 3;
            *(uint4*)(sA + r * 40 + cc) = *(const uint4*)(A + (size_t)(bm + r) * K + k0 + cc);
            *(uint4*)(sB + r * 40 + cc) = *(const uint4*)(Bt + (size_t)(bn + r) * K + k0 + cc);
        }
        __syncthreads();
        bf16x8 af[4], bfr[4];
        #pragma unroll
        for (int t = 0; t < 4; t++) {
            af[t]  = *(const bf16x8*)(sA + (wm + t * 16 + lr) * 40 + lq * 8);
            bfr[t] = *(const bf16x8*)(sB + (wn + t * 16 + lr) * 40 + lq * 8);
        }
        #pragma unroll
        for (int mt = 0; mt < 4; mt++)
            #pragma unroll
            for (int nt = 0; nt < 4; nt++)
                acc[mt][nt] = __builtin_amdgcn_mfma_f32_16x16x32_bf16(
                        af[mt], bfr[nt], acc[mt][nt], 0, 0, 0);
        __syncthreads();
    }
    #pragma unroll
    for (int mt = 0; mt < 4; mt++)
        #pragma unroll
        for (int nt = 0; nt < 4; nt++)
            #pragma unroll
            for (int r = 0; r < 4; r++) {
                int row = bm + wm + mt * 16 + lq * 4 + r;
                int orow = PERM ? ((row & 127) * 256 + n0 + (row >> 7)) : row;
                int col = bn + wn + nt * 16 + lr;
                float v = acc[mt][nt][r];
                if (EPI) {
                    float bv = flag ? ((const float*)bias)[col] : bf2f(((const u16*)bias)[col]);
                    size_t ri = res_off + (size_t)orow * N + col;
                    float rv = (RESF && flag) ? ((const float*)res)[ri]
                                              : bf2f(((const u16*)res)[ri]);
                    v += bv + rv;
                }
                size_t ci = c_off + (size_t)orow * N + col;
                if (OUTF && flag) ((float*)C)[ci] = v;
                else ((u16*)C)[ci] = f2bf(v);
            }
}

// ---------------- attention + output gating ----------------
// P: [rows][1024] bf16 = [q | k | v | g]. One block per (head, group). Thread i =
// query pos in group. rowi = i*istride + b*bstride; mask_idx = i*mi_s + b*mb_s + m_base.
template<bool HB, int L>
__global__ __launch_bounds__(256) void k_attn(
        const u16* __restrict__ P, const float* __restrict__ bias,
        const int* __restrict__ mask, const void* __restrict__ bg,
        u16* __restrict__ out, int istride, int bstride,
        int mi_s, int mb_s, int m_base, const int* __restrict__ flagp) {
    const int flag = *flagp;
    __shared__ float sk[L * 32];
    __shared__ u16   sv[L * 32];
    __shared__ float smk[L];
    const int h = blockIdx.x, b = blockIdx.y;
    const int i = threadIdx.x;
    const int rowi = i * istride + b * bstride;
    const u16* kp = P + (size_t)rowi * 1024 + 256 + h * 32;
    #pragma unroll
    for (int c = 0; c < 4; c++) {
        float kf[8];
        unpack8(*(const uint4*)(kp + c * 8), kf);
        *(float4*)(sk + i * 32 + c * 8)     = make_float4(kf[0], kf[1], kf[2], kf[3]);
        *(float4*)(sk + i * 32 + c * 8 + 4) = make_float4(kf[4], kf[5], kf[6], kf[7]);
        *(uint4*)(sv + i * 32 + c * 8) = *(const uint4*)(kp + 256 + c * 8);
    }
    const bool mi = mask[i * mi_s + b * mb_s + m_base] != 0;
    smk[i] = mi ? 1.f : 0.f;
    __syncthreads();

    float q[32];
    const u16* qp = P + (size_t)rowi * 1024 + h * 32;
    #pragma unroll
    for (int c = 0; c < 4; c++) unpack8(*(const uint4*)(qp + c * 8), q + c * 8);

    const float* bp = nullptr;
    if constexpr (HB) bp = bias + ((size_t)h * L + i) * L;

    float m = -1e30f, l = 0.f;
    float o[32];
    #pragma unroll
    for (int d = 0; d < 32; d++) o[d] = 0.f;

    for (int j = 0; j < L; j++) {
        const float* kj = sk + j * 32;
        float s = 0.f;
        #pragma unroll
        for (int d = 0; d < 32; d++) s += q[d] * kj[d];
        s *= 0.17677669529663687f;  // 1/sqrt(32)
        if constexpr (HB) s += bp[j];
        s = (mi && smk[j] > 0.f) ? s : -1e9f;
        float mn = fmaxf(m, s);
        float aexp = exp2f((m - mn) * 1.4426950408889634f);
        float p = exp2f((s - mn) * 1.4426950408889634f);
        l = l * aexp + p;
        const u16* vj = sv + j * 32;
        #pragma unroll
        for (int c = 0; c < 4; c++) {
            float vf[8];
            unpack8(*(const uint4*)(vj + c * 8), vf);
            #pragma unroll
            for (int e = 0; e < 8; e++)
                o[c * 8 + e] = o[c * 8 + e] * aexp + p * vf[e];
        }
        m = mn;
    }
    float inv = 1.f / l;
    const u16* gp = P + (size_t)rowi * 1024 + 768 + h * 32;
    u16* op = out + (size_t)rowi * 256 + h * 32;
    #pragma unroll
    for (int d = 0; d < 32; d++) {
        float bgv = flag ? ((const float*)bg)[h * 32 + d] : bf2f(((const u16*)bg)[h * 32 + d]);
        float g = bf2f(gp[d]) + bgv;
        float sig = 1.f / (1.f + exp2f(-g * 1.4426950408889634f));
        op[d] = f2bf(o[d] * inv * sig);
    }
}

extern "C" void kernel_launch(void* const* d_in, const int* in_sizes, int n_in,
                              void* d_out, int out_size, void* d_ws, size_t ws_size,
                              hipStream_t stream) {
    (void)in_sizes; (void)n_in; (void)out_size;
    const void* x        = d_in[0];
    const void* pw       = d_in[1];
    const int*  mask     = (const int*)d_in[2];
    const void* row_ln_g = d_in[3];
    const void* row_ln_b = d_in[4];
    const void* row_wq   = d_in[5];
    const void* row_wkv  = d_in[6];
    const void* row_wg   = d_in[7];
    const void* row_bg   = d_in[8];
    const void* row_wo   = d_in[9];
    const void* row_bo   = d_in[10];
    const void* row_we   = d_in[11];
    const void* col_ln_g = d_in[12];
    const void* col_ln_b = d_in[13];
    const void* col_wq   = d_in[14];
    const void* col_wkv  = d_in[15];
    const void* col_wg   = d_in[16];
    const void* col_bg   = d_in[17];
    const void* col_wo   = d_in[18];
    const void* col_bo   = d_in[19];

    // choose chunking from ws_size (host-side, capture-stable):
    // full (nc=1) needs ~120.2 MB; fallback nc=8 needs ~30.6 MB (proven).
    const int nc = (ws_size >= 120193536u) ? 1 : 8;
    const int rows = 32768 / nc;          // rows per chunk

    char* ws = (char*)d_ws;
    size_t off = 0;
    int*   flagp  = (int*)(ws + off);  off += 512;
    u16*   Wt     = (u16*)(ws + off);  off += 524288;      // [1024][256] bf16
    u16*   WoT    = (u16*)(ws + off);  off += 131072;      // [256][256] bf16
    float* biasb  = (float*)(ws + off); off += 2097152;    // [8][256][256] fp32
    u16*   xn_c   = (u16*)(ws + off);  off += (size_t)rows * 512;   // bf16
    u16*   attn_c = (u16*)(ws + off);  off += (size_t)rows * 512;   // bf16
    u16*   P_c    = (u16*)(ws + off);  off += (size_t)rows * 2048;  // bf16
    u16*   x1     = (u16*)(ws + off);  off += 16777216;    // [32768][256] bf16

    k_flag<<<1, 256, 0, stream>>>(x, flagp);

    // ---------------- stage 1: row attention (x1 in ws, bf16) ----------------
    k_tr<<<256, 256, 0, stream>>>(row_wq,  Wt,             256, 256, flagp);
    k_tr<<<512, 256, 0, stream>>>(row_wkv, Wt + 256 * 256, 256, 512, flagp);
    k_tr<<<256, 256, 0, stream>>>(row_wg,  Wt + 768 * 256, 256, 256, flagp);
    k_tr<<<256, 256, 0, stream>>>(row_wo,  WoT,            256, 256, flagp);
    k_bias<<<256, 256, 0, stream>>>(pw, row_we, biasb, flagp);
    for (int c = 0; c < nc; c++) {
        const int s0 = c * (128 / nc);    // first MSA row of chunk
        k_ln<<<rows / 4, 256, 0, stream>>>(x, row_ln_g, row_ln_b, xn_c,
                                           128, 1, s0 * 256, flagp, 1);
        k_gemm<false, false, false, false><<<dim3(rows / 128, 8), 256, 0, stream>>>(
                xn_c, Wt, P_c, 0, 1024, nullptr, nullptr, 0, 0, flagp);
        k_attn<true, 256><<<dim3(8, 128 / nc), 256, 0, stream>>>(
                P_c, biasb, mask, row_bg, attn_c, 1, 256, 1, 256, s0 * 256, flagp);
        k_gemm<true, false, true, false><<<dim3(rows / 128, 2), 256, 0, stream>>>(
                attn_c, WoT, x1, (size_t)s0 * 65536, 256,
                row_bo, x, (size_t)s0 * 65536, 0, flagp);
    }

    // ---------------- stage 2: column attention (reads x1 bf16, writes d_out) ----------------
    k_tr<<<256, 256, 0, stream>>>(col_wq,  Wt,             256, 256, flagp);
    k_tr<<<512, 256, 0, stream>>>(col_wkv, Wt + 256 * 256, 256, 512, flagp);
    k_tr<<<256, 256, 0, stream>>>(col_wg,  Wt + 768 * 256, 256, 256, flagp);
    k_tr<<<256, 256, 0, stream>>>(col_wo,  WoT,            256, 256, flagp);
    for (int c = 0; c < nc; c++) {
        const int n0 = c * (256 / nc);    // first residue column of chunk
        k_ln<<<rows / 4, 256, 0, stream>>>(x1, col_ln_g, col_ln_b, xn_c,
                                           1, 256, n0, flagp, 0);
        k_gemm<false, false, false, false><<<dim3(rows / 128, 8), 256, 0, stream>>>(
                xn_c, Wt, P_c, 0, 1024, nullptr, nullptr, 0, 0, flagp);
        k_attn<false, 128><<<dim3(8, 256 / nc), 128, 0, stream>>>(
                P_c, nullptr, mask, col_bg, attn_c, 1, 128, 256, 1, n0, flagp);
        k_gemm<true, true, false, true><<<dim3(rows / 128, 2), 256, 0, stream>>>(
                attn_c, WoT, d_out, 0, 256, col_bo, x1, 0, n0, flagp);
    }
}

// Round 5
// 576.123 us; speedup vs baseline: 3.7291x; 1.4213x over previous
//
#include <hip/hip_runtime.h>

typedef unsigned short u16;
typedef unsigned int u32;
typedef __bf16 bf16x8 __attribute__((ext_vector_type(8)));
typedef float f32x4 __attribute__((ext_vector_type(4)));

__device__ __forceinline__ float bf2f(u16 u) {
    union { u32 u; float f; } x; x.u = ((u32)u) << 16; return x.f;
}
__device__ __forceinline__ u16 f2bf(float f) {
    union { float f; u32 u; } x; x.f = f;
    u32 r = x.u + 0x7fffu + ((x.u >> 16) & 1u);
    return (u16)(r >> 16);
}
__device__ __forceinline__ void unpack8(uint4 d, float* f) {
    f[0] = bf2f((u16)(d.x & 0xffffu)); f[1] = bf2f((u16)(d.x >> 16));
    f[2] = bf2f((u16)(d.y & 0xffffu)); f[3] = bf2f((u16)(d.y >> 16));
    f[4] = bf2f((u16)(d.z & 0xffffu)); f[5] = bf2f((u16)(d.z >> 16));
    f[6] = bf2f((u16)(d.w & 0xffffu)); f[7] = bf2f((u16)(d.w >> 16));
}

// ---- dtype sniffing: fp32 data read as bf16 halfwords has wild exponents ----
__global__ __launch_bounds__(256) void k_flag(const void* __restrict__ x, int* __restrict__ flag) {
    const u16* p = (const u16*)x;
    const int t = threadIdx.x;
    float mx = 0.f;
    for (int i = t; i < 4096; i += 256) {
        float v = fabsf(bf2f(p[i]));
        if (!(v < 1e30f)) v = 1e30f;  // NaN/Inf -> big
        mx = fmaxf(mx, v);
    }
    __shared__ float red[256];
    red[t] = mx; __syncthreads();
    for (int s = 128; s > 0; s >>= 1) {
        if (t < s) red[t] = fmaxf(red[t], red[t + s]);
        __syncthreads();
    }
    if (t == 0) *flag = (red[0] > 1e6f) ? 1 : 0;  // 1 = fp32, 0 = bf16
}

// ---------------- weight transpose+convert: Wt[n*K+k] = bf16(W[k*N+n]) ----------------
__global__ void k_tr(const void* __restrict__ W, u16* __restrict__ Wt, int K, int N,
                     const int* __restrict__ flagp) {
    const int flag = *flagp;
    int idx = blockIdx.x * 256 + threadIdx.x;
    if (idx < K * N) {
        int k = idx / N, n = idx - k * N;
        u16 v = flag ? f2bf(((const float*)W)[idx]) : ((const u16*)W)[idx];
        Wt[n * K + k] = v;
    }
}

// ---------------- LayerNorm over D=256, one wave per local row ----------------
// in_row = (r>>7)*so + (r&127)*si + base;  out row r dense bf16.
// xmode: 1 -> x has flag dtype; 0 -> x is always bf16 (internal buffer).
__global__ __launch_bounds__(256) void k_ln(
        const void* __restrict__ x, const void* __restrict__ g,
        const void* __restrict__ b, u16* __restrict__ xn,
        int so, int si, int base, const int* __restrict__ flagp, int xmode) {
    const int flag = *flagp;
    const int xf = xmode ? flag : 0;
    const int wave = threadIdx.x >> 6, lane = threadIdx.x & 63;
    const int r = blockIdx.x * 4 + wave;
    const int in_row = (r >> 7) * so + (r & 127) * si + base;
    const size_t off = (size_t)in_row * 256 + lane * 4;
    float v[4];
    if (xf) {
        float4 d = *(const float4*)((const float*)x + off);
        v[0] = d.x; v[1] = d.y; v[2] = d.z; v[3] = d.w;
    } else {
        uint2 d = *(const uint2*)((const u16*)x + off);
        v[0] = bf2f((u16)(d.x & 0xffffu)); v[1] = bf2f((u16)(d.x >> 16));
        v[2] = bf2f((u16)(d.y & 0xffffu)); v[3] = bf2f((u16)(d.y >> 16));
    }
    float s = v[0] + v[1] + v[2] + v[3];
    #pragma unroll
    for (int o2 = 32; o2 > 0; o2 >>= 1) s += __shfl_xor(s, o2, 64);
    float mu = s * (1.f / 256.f);
    float vs = 0.f;
    #pragma unroll
    for (int e = 0; e < 4; e++) { float t = v[e] - mu; vs += t * t; }
    #pragma unroll
    for (int o2 = 32; o2 > 0; o2 >>= 1) vs += __shfl_xor(vs, o2, 64);
    float rr = rsqrtf(vs * (1.f / 256.f) + 1e-5f);
    float gf[4], bf_[4];
    if (flag) {
        float4 gg = *(const float4*)((const float*)g + lane * 4);
        float4 bb = *(const float4*)((const float*)b + lane * 4);
        gf[0] = gg.x; gf[1] = gg.y; gf[2] = gg.z; gf[3] = gg.w;
        bf_[0] = bb.x; bf_[1] = bb.y; bf_[2] = bb.z; bf_[3] = bb.w;
    } else {
        uint2 gg = *(const uint2*)((const u16*)g + lane * 4);
        uint2 bb = *(const uint2*)((const u16*)b + lane * 4);
        gf[0] = bf2f((u16)(gg.x & 0xffffu)); gf[1] = bf2f((u16)(gg.x >> 16));
        gf[2] = bf2f((u16)(gg.y & 0xffffu)); gf[3] = bf2f((u16)(gg.y >> 16));
        bf_[0] = bf2f((u16)(bb.x & 0xffffu)); bf_[1] = bf2f((u16)(bb.x >> 16));
        bf_[2] = bf2f((u16)(bb.y & 0xffffu)); bf_[3] = bf2f((u16)(bb.y >> 16));
    }
    u16 o[4];
    #pragma unroll
    for (int e = 0; e < 4; e++) o[e] = f2bf((v[e] - mu) * rr * gf[e] + bf_[e]);
    uint2 ov;
    ov.x = (u32)o[0] | ((u32)o[1] << 16);
    ov.y = (u32)o[2] | ((u32)o[3] << 16);
    *(uint2*)(xn + (size_t)r * 256 + lane * 4) = ov;
}

// ------------- pairwise bias: bias[h][i][j] = sum_d pw[i][j][d]*we[d][h] -------------
__global__ __launch_bounds__(256) void k_bias(
        const void* __restrict__ pw, const void* __restrict__ we,
        float* __restrict__ bias, const int* __restrict__ flagp) {
    const int flag = *flagp;
    __shared__ float swe[2048];  // [256][8] fp32
    for (int t = threadIdx.x; t < 2048; t += 256)
        swe[t] = flag ? ((const float*)we)[t] : bf2f(((const u16*)we)[t]);
    __syncthreads();
    const int i = blockIdx.x, j = threadIdx.x;
    const size_t rowoff = ((size_t)i * 256 + j) * 256;
    float acc[8] = {0.f, 0.f, 0.f, 0.f, 0.f, 0.f, 0.f, 0.f};
    for (int d0 = 0; d0 < 256; d0 += 8) {
        float f[8];
        if (flag) {
            const float* p32 = (const float*)pw + rowoff + d0;
            float4 a = *(const float4*)p32;
            float4 b = *(const float4*)(p32 + 4);
            f[0] = a.x; f[1] = a.y; f[2] = a.z; f[3] = a.w;
            f[4] = b.x; f[5] = b.y; f[6] = b.z; f[7] = b.w;
        } else {
            unpack8(*(const uint4*)((const u16*)pw + rowoff + d0), f);
        }
        #pragma unroll
        for (int e = 0; e < 8; e++) {
            const float* w = swe + (d0 + e) * 8;
            #pragma unroll
            for (int hh = 0; hh < 8; hh++) acc[hh] += f[e] * w[hh];
        }
    }
    #pragma unroll
    for (int hh = 0; hh < 8; hh++)
        bias[((size_t)hh * 256 + i) * 256 + j] = acc[hh];
}

// ---------------- MFMA GEMM: C[M,N] = A[M,256] @ Bt[N,256]^T ----------------
template<bool EPI, bool PERM, bool RESF, bool OUTF>
__global__ __launch_bounds__(256, 2) void k_gemm(
        const u16* __restrict__ A, const u16* __restrict__ Bt, void* __restrict__ C,
        size_t c_off, int N, const void* __restrict__ bias,
        const void* __restrict__ res, size_t res_off, int n0,
        const int* __restrict__ flagp) {
    constexpr int K = 256;
    const int flag = *flagp;
    __shared__ u16 sA[128 * 40];
    __shared__ u16 sB[128 * 40];
    const int tid = threadIdx.x;
    const int bm = blockIdx.x * 128, bn = blockIdx.y * 128;
    const int wave = tid >> 6, lane = tid & 63;
    const int wm = (wave >> 1) * 64, wn = (wave & 1) * 64;
    const int lr = lane & 15, lq = lane >> 4;
    f32x4 acc[4][4];
    #pragma unroll
    for (int a = 0; a < 4; a++)
        #pragma unroll
        for (int b2 = 0; b2 < 4; b2++) {
            acc[a][b2][0] = 0.f; acc[a][b2][1] = 0.f;
            acc[a][b2][2] = 0.f; acc[a][b2][3] = 0.f;
        }
    for (int k0 = 0; k0 < K; k0 += 32) {
        for (int c = tid; c < 512; c += 256) {
            int r = c >> 2, cc = (c & 3) << 3;
            *(uint4*)(sA + r * 40 + cc) = *(const uint4*)(A + (size_t)(bm + r) * K + k0 + cc);
            *(uint4*)(sB + r * 40 + cc) = *(const uint4*)(Bt + (size_t)(bn + r) * K + k0 + cc);
        }
        __syncthreads();
        bf16x8 af[4], bfr[4];
        #pragma unroll
        for (int t = 0; t < 4; t++) {
            af[t]  = *(const bf16x8*)(sA + (wm + t * 16 + lr) * 40 + lq * 8);
            bfr[t] = *(const bf16x8*)(sB + (wn + t * 16 + lr) * 40 + lq * 8);
        }
        #pragma unroll
        for (int mt = 0; mt < 4; mt++)
            #pragma unroll
            for (int nt = 0; nt < 4; nt++)
                acc[mt][nt] = __builtin_amdgcn_mfma_f32_16x16x32_bf16(
                        af[mt], bfr[nt], acc[mt][nt], 0, 0, 0);
        __syncthreads();
    }
    #pragma unroll
    for (int mt = 0; mt < 4; mt++)
        #pragma unroll
        for (int nt = 0; nt < 4; nt++)
            #pragma unroll
            for (int r = 0; r < 4; r++) {
                int row = bm + wm + mt * 16 + lq * 4 + r;
                int orow = PERM ? ((row & 127) * 256 + n0 + (row >> 7)) : row;
                int col = bn + wn + nt * 16 + lr;
                float v = acc[mt][nt][r];
                if (EPI) {
                    float bv = flag ? ((const float*)bias)[col] : bf2f(((const u16*)bias)[col]);
                    size_t ri = res_off + (size_t)orow * N + col;
                    float rv = (RESF && flag) ? ((const float*)res)[ri]
                                              : bf2f(((const u16*)res)[ri]);
                    v += bv + rv;
                }
                size_t ci = c_off + (size_t)orow * N + col;
                if (OUTF && flag) ((float*)C)[ci] = v;
                else ((u16*)C)[ci] = f2bf(v);
            }
}

// ---------------- MFMA flash attention + output gating ----------------
// P: [rows][1024] bf16 = [q|k|v|g]. Block = (head h, group b); group rows are
// P[b*bstride + i], i in [0,L). Each wave owns 64 queries. S = Q·K^T via
// 16x16x32 MFMA (K=d=32), online softmax on C-layout frags, P->A-layout via
// per-wave LDS scratch, O += P·V^T via MFMA with V^T staged in LDS.
// mask_idx = i*mi_s + b*mb_s + m_base.
template<bool HB, int L>
__global__ __launch_bounds__(L) void k_attn_mfma(
        const u16* __restrict__ P, const float* __restrict__ bias,
        const int* __restrict__ mask, const void* __restrict__ bg,
        u16* __restrict__ out, int bstride, int mi_s, int mb_s, int m_base,
        const int* __restrict__ flagp) {
    constexpr int WAVES = L / 64;
    constexpr int VROW = L + 8;       // svt row stride (2-way banks only)
    __shared__ u16 sk[L * 40];        // K rows [L][32] pad 40
    __shared__ u16 svt[32 * VROW];    // V^T [32][L]
    __shared__ u16 pscr[WAVES * 64 * 40];  // per-wave P scratch [64][32] pad 40
    __shared__ float smk[L];
    const int flag = *flagp;
    const int h = blockIdx.x, b = blockIdx.y;
    const int tid = threadIdx.x;

    // ---- stage K rows, V^T, mask ----
    {
        const size_t prow = (size_t)(b * bstride + tid) * 1024 + h * 32;
        const u16* kp = P + prow + 256;
        #pragma unroll
        for (int c = 0; c < 4; c++)
            *(uint4*)(sk + tid * 40 + c * 8) = *(const uint4*)(kp + c * 8);
        const u16* vp = P + prow + 512;
        #pragma unroll
        for (int c = 0; c < 4; c++) {
            uint4 d = *(const uint4*)(vp + c * 8);
            u16 hw[8];
            hw[0] = (u16)(d.x & 0xffffu); hw[1] = (u16)(d.x >> 16);
            hw[2] = (u16)(d.y & 0xffffu); hw[3] = (u16)(d.y >> 16);
            hw[4] = (u16)(d.z & 0xffffu); hw[5] = (u16)(d.z >> 16);
            hw[6] = (u16)(d.w & 0xffffu); hw[7] = (u16)(d.w >> 16);
            #pragma unroll
            for (int e = 0; e < 8; e++)
                svt[(c * 8 + e) * VROW + tid] = hw[e];
        }
        smk[tid] = (mask[tid * mi_s + b * mb_s + m_base] != 0) ? 1.f : 0.f;
    }
    __syncthreads();

    const int wave = tid >> 6, lane = tid & 63;
    const int lq = lane >> 4, lr = lane & 15;
    const int qbase = wave * 64;
    u16* pw = pscr + wave * 64 * 40;

    // Q fragments (A-layout: m=lane&15, k=lq*8..+8), constant over chunks
    bf16x8 af[4];
    #pragma unroll
    for (int qt = 0; qt < 4; qt++) {
        const size_t qrow = (size_t)(b * bstride + qbase + qt * 16 + lr) * 1024 + h * 32;
        af[qt] = *(const bf16x8*)(P + qrow + lq * 8);
    }
    float qm[4][4];
    #pragma unroll
    for (int qt = 0; qt < 4; qt++)
        #pragma unroll
        for (int r = 0; r < 4; r++)
            qm[qt][r] = smk[qbase + qt * 16 + lq * 4 + r];

    f32x4 o[4][2];
    float mrun[4][4], lrun[4][4];
    #pragma unroll
    for (int qt = 0; qt < 4; qt++) {
        #pragma unroll
        for (int dt = 0; dt < 2; dt++) {
            o[qt][dt][0] = 0.f; o[qt][dt][1] = 0.f; o[qt][dt][2] = 0.f; o[qt][dt][3] = 0.f;
        }
        #pragma unroll
        for (int r = 0; r < 4; r++) { mrun[qt][r] = -1e30f; lrun[qt][r] = 0.f; }
    }

    const f32x4 zero = {0.f, 0.f, 0.f, 0.f};
    for (int j0 = 0; j0 < L; j0 += 32) {
        // S = Q K^T for 2 key tiles of 16
        bf16x8 bk0 = *(const bf16x8*)(sk + (j0 + lr) * 40 + lq * 8);
        bf16x8 bk1 = *(const bf16x8*)(sk + (j0 + 16 + lr) * 40 + lq * 8);
        float km0 = smk[j0 + lr], km1 = smk[j0 + 16 + lr];
        f32x4 s0[4], s1[4];
        #pragma unroll
        for (int qt = 0; qt < 4; qt++) {
            s0[qt] = __builtin_amdgcn_mfma_f32_16x16x32_bf16(af[qt], bk0, zero, 0, 0, 0);
            s1[qt] = __builtin_amdgcn_mfma_f32_16x16x32_bf16(af[qt], bk1, zero, 0, 0, 0);
        }
        #pragma unroll
        for (int qt = 0; qt < 4; qt++) {
            #pragma unroll
            for (int r = 0; r < 4; r++) {
                const int ql = qbase + qt * 16 + lq * 4 + r;  // query index in group
                float a = s0[qt][r] * 0.17677669529663687f;
                float c = s1[qt][r] * 0.17677669529663687f;
                if (HB) {
                    const float* bp = bias + ((size_t)(h * 256 + ql)) * 256 + j0;
                    a += bp[lr];
                    c += bp[16 + lr];
                }
                const bool qv = qm[qt][r] > 0.f;
                a = (qv && km0 > 0.f) ? a : -1e9f;
                c = (qv && km1 > 0.f) ? c : -1e9f;
                float t = fmaxf(a, c);
                t = fmaxf(t, __shfl_xor(t, 1, 64));
                t = fmaxf(t, __shfl_xor(t, 2, 64));
                t = fmaxf(t, __shfl_xor(t, 4, 64));
                t = fmaxf(t, __shfl_xor(t, 8, 64));
                const float mn = fmaxf(mrun[qt][r], t);
                const float aexp = exp2f((mrun[qt][r] - mn) * 1.4426950408889634f);
                mrun[qt][r] = mn;
                const float p0 = exp2f((a - mn) * 1.4426950408889634f);
                const float p1 = exp2f((c - mn) * 1.4426950408889634f);
                float rs = p0 + p1;
                rs += __shfl_xor(rs, 1, 64);
                rs += __shfl_xor(rs, 2, 64);
                rs += __shfl_xor(rs, 4, 64);
                rs += __shfl_xor(rs, 8, 64);
                lrun[qt][r] = lrun[qt][r] * aexp + rs;
                union { float f; u32 u; } x0, x1;
                x0.f = p0; x1.f = p1;
                const int prow = (qt * 16 + lq * 4 + r) * 40;
                pw[prow + lr]      = (u16)((x0.u + 0x8000u) >> 16);
                pw[prow + 16 + lr] = (u16)((x1.u + 0x8000u) >> 16);
                o[qt][0][r] *= aexp;
                o[qt][1][r] *= aexp;
            }
        }
        __syncthreads();  // pscr write -> A-frag read (cross-lane visibility)
        bf16x8 vb0 = *(const bf16x8*)(svt + (size_t)lr * VROW + j0 + lq * 8);
        bf16x8 vb1 = *(const bf16x8*)(svt + (size_t)(16 + lr) * VROW + j0 + lq * 8);
        #pragma unroll
        for (int qt = 0; qt < 4; qt++) {
            bf16x8 pa = *(const bf16x8*)(pw + (qt * 16 + lr) * 40 + lq * 8);
            o[qt][0] = __builtin_amdgcn_mfma_f32_16x16x32_bf16(pa, vb0, o[qt][0], 0, 0, 0);
            o[qt][1] = __builtin_amdgcn_mfma_f32_16x16x32_bf16(pa, vb1, o[qt][1], 0, 0, 0);
        }
        __syncthreads();
    }

    // ---- epilogue: 1/l, gate sigmoid, store bf16 ----
    float bgv[2];
    #pragma unroll
    for (int dt = 0; dt < 2; dt++)
        bgv[dt] = flag ? ((const float*)bg)[h * 32 + dt * 16 + lr]
                       : bf2f(((const u16*)bg)[h * 32 + dt * 16 + lr]);
    #pragma unroll
    for (int qt = 0; qt < 4; qt++)
        #pragma unroll
        for (int r = 0; r < 4; r++) {
            const float inv = 1.f / lrun[qt][r];
            const size_t row = (size_t)(b * bstride + qbase + qt * 16 + lq * 4 + r);
            const u16* gp = P + row * 1024 + 768 + h * 32;
            u16* op = out + row * 256 + h * 32;
            #pragma unroll
            for (int dt = 0; dt < 2; dt++) {
                const float g = bf2f(gp[dt * 16 + lr]) + bgv[dt];
                const float sig = 1.f / (1.f + exp2f(-g * 1.4426950408889634f));
                op[dt * 16 + lr] = f2bf(o[qt][dt][r] * inv * sig);
            }
        }
}

extern "C" void kernel_launch(void* const* d_in, const int* in_sizes, int n_in,
                              void* d_out, int out_size, void* d_ws, size_t ws_size,
                              hipStream_t stream) {
    (void)in_sizes; (void)n_in; (void)out_size;
    const void* x        = d_in[0];
    const void* pw       = d_in[1];
    const int*  mask     = (const int*)d_in[2];
    const void* row_ln_g = d_in[3];
    const void* row_ln_b = d_in[4];
    const void* row_wq   = d_in[5];
    const void* row_wkv  = d_in[6];
    const void* row_wg   = d_in[7];
    const void* row_bg   = d_in[8];
    const void* row_wo   = d_in[9];
    const void* row_bo   = d_in[10];
    const void* row_we   = d_in[11];
    const void* col_ln_g = d_in[12];
    const void* col_ln_b = d_in[13];
    const void* col_wq   = d_in[14];
    const void* col_wkv  = d_in[15];
    const void* col_wg   = d_in[16];
    const void* col_bg   = d_in[17];
    const void* col_wo   = d_in[18];
    const void* col_bo   = d_in[19];

    // choose chunking from ws_size (host-side, capture-stable):
    const int nc = (ws_size >= 120193536u) ? 1 : 8;
    const int rows = 32768 / nc;          // rows per chunk

    char* ws = (char*)d_ws;
    size_t off = 0;
    int*   flagp  = (int*)(ws + off);  off += 512;
    u16*   Wt     = (u16*)(ws + off);  off += 524288;      // [1024][256] bf16
    u16*   WoT    = (u16*)(ws + off);  off += 131072;      // [256][256] bf16
    float* biasb  = (float*)(ws + off); off += 2097152;    // [8][256][256] fp32
    u16*   xn_c   = (u16*)(ws + off);  off += (size_t)rows * 512;   // bf16
    u16*   attn_c = (u16*)(ws + off);  off += (size_t)rows * 512;   // bf16
    u16*   P_c    = (u16*)(ws + off);  off += (size_t)rows * 2048;  // bf16
    u16*   x1     = (u16*)(ws + off);  off += 16777216;    // [32768][256] bf16

    k_flag<<<1, 256, 0, stream>>>(x, flagp);

    // ---------------- stage 1: row attention (x1 in ws, bf16) ----------------
    k_tr<<<256, 256, 0, stream>>>(row_wq,  Wt,             256, 256, flagp);
    k_tr<<<512, 256, 0, stream>>>(row_wkv, Wt + 256 * 256, 256, 512, flagp);
    k_tr<<<256, 256, 0, stream>>>(row_wg,  Wt + 768 * 256, 256, 256, flagp);
    k_tr<<<256, 256, 0, stream>>>(row_wo,  WoT,            256, 256, flagp);
    k_bias<<<256, 256, 0, stream>>>(pw, row_we, biasb, flagp);
    for (int c = 0; c < nc; c++) {
        const int s0 = c * (128 / nc);    // first MSA row of chunk
        k_ln<<<rows / 4, 256, 0, stream>>>(x, row_ln_g, row_ln_b, xn_c,
                                           128, 1, s0 * 256, flagp, 1);
        k_gemm<false, false, false, false><<<dim3(rows / 128, 8), 256, 0, stream>>>(
                xn_c, Wt, P_c, 0, 1024, nullptr, nullptr, 0, 0, flagp);
        k_attn_mfma<true, 256><<<dim3(8, 128 / nc), 256, 0, stream>>>(
                P_c, biasb, mask, row_bg, attn_c, 256, 1, 256, s0 * 256, flagp);
        k_gemm<true, false, true, false><<<dim3(rows / 128, 2), 256, 0, stream>>>(
                attn_c, WoT, x1, (size_t)s0 * 65536, 256,
                row_bo, x, (size_t)s0 * 65536, 0, flagp);
    }

    // ---------------- stage 2: column attention (reads x1 bf16, writes d_out) ----------------
    k_tr<<<256, 256, 0, stream>>>(col_wq,  Wt,             256, 256, flagp);
    k_tr<<<512, 256, 0, stream>>>(col_wkv, Wt + 256 * 256, 256, 512, flagp);
    k_tr<<<256, 256, 0, stream>>>(col_wg,  Wt + 768 * 256, 256, 256, flagp);
    k_tr<<<256, 256, 0, stream>>>(col_wo,  WoT,            256, 256, flagp);
    for (int c = 0; c < nc; c++) {
        const int n0 = c * (256 / nc);    // first residue column of chunk
        k_ln<<<rows / 4, 256, 0, stream>>>(x1, col_ln_g, col_ln_b, xn_c,
                                           1, 256, n0, flagp, 0);
        k_gemm<false, false, false, false><<<dim3(rows / 128, 8), 256, 0, stream>>>(
                xn_c, Wt, P_c, 0, 1024, nullptr, nullptr, 0, 0, flagp);
        k_attn_mfma<false, 128><<<dim3(8, 256 / nc), 128, 0, stream>>>(
                P_c, nullptr, mask, col_bg, attn_c, 128, 256, 1, n0, flagp);
        k_gemm<true, true, false, true><<<dim3(rows / 128, 2), 256, 0, stream>>>(
                attn_c, WoT, d_out, 0, 256, col_bo, x1, 0, n0, flagp);
    }
}

// Round 6
// 496.722 us; speedup vs baseline: 4.3252x; 1.1599x over previous
//
#include <hip/hip_runtime.h>

typedef unsigned short u16;
typedef unsigned int u32;
typedef __bf16 bf16x8 __attribute__((ext_vector_type(8)));
typedef float f32x4 __attribute__((ext_vector_type(4)));

__device__ __forceinline__ float bf2f(u16 u) {
    union { u32 u; float f; } x; x.u = ((u32)u) << 16; return x.f;
}
__device__ __forceinline__ u16 f2bf(float f) {
    union { float f; u32 u; } x; x.f = f;
    u32 r = x.u + 0x7fffu + ((x.u >> 16) & 1u);
    return (u16)(r >> 16);
}
__device__ __forceinline__ void unpack8(uint4 d, float* f) {
    f[0] = bf2f((u16)(d.x & 0xffffu)); f[1] = bf2f((u16)(d.x >> 16));
    f[2] = bf2f((u16)(d.y & 0xffffu)); f[3] = bf2f((u16)(d.y >> 16));
    f[4] = bf2f((u16)(d.z & 0xffffu)); f[5] = bf2f((u16)(d.z >> 16));
    f[6] = bf2f((u16)(d.w & 0xffffu)); f[7] = bf2f((u16)(d.w >> 16));
}

// ---- dtype sniffing: fp32 data read as bf16 halfwords has wild exponents ----
__global__ __launch_bounds__(256) void k_flag(const void* __restrict__ x, int* __restrict__ flag) {
    const u16* p = (const u16*)x;
    const int t = threadIdx.x;
    float mx = 0.f;
    for (int i = t; i < 4096; i += 256) {
        float v = fabsf(bf2f(p[i]));
        if (!(v < 1e30f)) v = 1e30f;  // NaN/Inf -> big
        mx = fmaxf(mx, v);
    }
    __shared__ float red[256];
    red[t] = mx; __syncthreads();
    for (int s = 128; s > 0; s >>= 1) {
        if (t < s) red[t] = fmaxf(red[t], red[t + s]);
        __syncthreads();
    }
    if (t == 0) *flag = (red[0] > 1e6f) ? 1 : 0;  // 1 = fp32, 0 = bf16
}

// ---------------- weight transpose+convert: Wt[n*K+k] = bf16(W[k*N+n]) ----------------
__global__ void k_tr(const void* __restrict__ W, u16* __restrict__ Wt, int K, int N,
                     const int* __restrict__ flagp) {
    const int flag = *flagp;
    int idx = blockIdx.x * 256 + threadIdx.x;
    if (idx < K * N) {
        int k = idx / N, n = idx - k * N;
        u16 v = flag ? f2bf(((const float*)W)[idx]) : ((const u16*)W)[idx];
        Wt[n * K + k] = v;
    }
}

// ---------------- LayerNorm over D=256, one wave per local row ----------------
__global__ __launch_bounds__(256) void k_ln(
        const void* __restrict__ x, const void* __restrict__ g,
        const void* __restrict__ b, u16* __restrict__ xn,
        int so, int si, int base, const int* __restrict__ flagp, int xmode) {
    const int flag = *flagp;
    const int xf = xmode ? flag : 0;
    const int wave = threadIdx.x >> 6, lane = threadIdx.x & 63;
    const int r = blockIdx.x * 4 + wave;
    const int in_row = (r >> 7) * so + (r & 127) * si + base;
    const size_t off = (size_t)in_row * 256 + lane * 4;
    float v[4];
    if (xf) {
        float4 d = *(const float4*)((const float*)x + off);
        v[0] = d.x; v[1] = d.y; v[2] = d.z; v[3] = d.w;
    } else {
        uint2 d = *(const uint2*)((const u16*)x + off);
        v[0] = bf2f((u16)(d.x & 0xffffu)); v[1] = bf2f((u16)(d.x >> 16));
        v[2] = bf2f((u16)(d.y & 0xffffu)); v[3] = bf2f((u16)(d.y >> 16));
    }
    float s = v[0] + v[1] + v[2] + v[3];
    #pragma unroll
    for (int o2 = 32; o2 > 0; o2 >>= 1) s += __shfl_xor(s, o2, 64);
    float mu = s * (1.f / 256.f);
    float vs = 0.f;
    #pragma unroll
    for (int e = 0; e < 4; e++) { float t = v[e] - mu; vs += t * t; }
    #pragma unroll
    for (int o2 = 32; o2 > 0; o2 >>= 1) vs += __shfl_xor(vs, o2, 64);
    float rr = rsqrtf(vs * (1.f / 256.f) + 1e-5f);
    float gf[4], bf_[4];
    if (flag) {
        float4 gg = *(const float4*)((const float*)g + lane * 4);
        float4 bb = *(const float4*)((const float*)b + lane * 4);
        gf[0] = gg.x; gf[1] = gg.y; gf[2] = gg.z; gf[3] = gg.w;
        bf_[0] = bb.x; bf_[1] = bb.y; bf_[2] = bb.z; bf_[3] = bb.w;
    } else {
        uint2 gg = *(const uint2*)((const u16*)g + lane * 4);
        uint2 bb = *(const uint2*)((const u16*)b + lane * 4);
        gf[0] = bf2f((u16)(gg.x & 0xffffu)); gf[1] = bf2f((u16)(gg.x >> 16));
        gf[2] = bf2f((u16)(gg.y & 0xffffu)); gf[3] = bf2f((u16)(gg.y >> 16));
        bf_[0] = bf2f((u16)(bb.x & 0xffffu)); bf_[1] = bf2f((u16)(bb.x >> 16));
        bf_[2] = bf2f((u16)(bb.y & 0xffffu)); bf_[3] = bf2f((u16)(bb.y >> 16));
    }
    u16 o[4];
    #pragma unroll
    for (int e = 0; e < 4; e++) o[e] = f2bf((v[e] - mu) * rr * gf[e] + bf_[e]);
    uint2 ov;
    ov.x = (u32)o[0] | ((u32)o[1] << 16);
    ov.y = (u32)o[2] | ((u32)o[3] << 16);
    *(uint2*)(xn + (size_t)r * 256 + lane * 4) = ov;
}

// ------------- pairwise bias: bias[h][i][j] = sum_d pw[i][j][d]*we[d][h] -------------
__global__ __launch_bounds__(256) void k_bias(
        const void* __restrict__ pw, const void* __restrict__ we,
        float* __restrict__ bias, const int* __restrict__ flagp) {
    const int flag = *flagp;
    __shared__ float swe[2048];  // [256][8] fp32
    for (int t = threadIdx.x; t < 2048; t += 256)
        swe[t] = flag ? ((const float*)we)[t] : bf2f(((const u16*)we)[t]);
    __syncthreads();
    const int i = blockIdx.x, j = threadIdx.x;
    const size_t rowoff = ((size_t)i * 256 + j) * 256;
    float acc[8] = {0.f, 0.f, 0.f, 0.f, 0.f, 0.f, 0.f, 0.f};
    for (int d0 = 0; d0 < 256; d0 += 8) {
        float f[8];
        if (flag) {
            const float* p32 = (const float*)pw + rowoff + d0;
            float4 a = *(const float4*)p32;
            float4 b = *(const float4*)(p32 + 4);
            f[0] = a.x; f[1] = a.y; f[2] = a.z; f[3] = a.w;
            f[4] = b.x; f[5] = b.y; f[6] = b.z; f[7] = b.w;
        } else {
            unpack8(*(const uint4*)((const u16*)pw + rowoff + d0), f);
        }
        #pragma unroll
        for (int e = 0; e < 8; e++) {
            const float* w = swe + (d0 + e) * 8;
            #pragma unroll
            for (int hh = 0; hh < 8; hh++) acc[hh] += f[e] * w[hh];
        }
    }
    #pragma unroll
    for (int hh = 0; hh < 8; hh++)
        bias[((size_t)hh * 256 + i) * 256 + j] = acc[hh];
}

// ---------------- MFMA GEMM: C[M,N] = A[M,256] @ Bt[N,256]^T ----------------
template<bool EPI, bool PERM, bool RESF, bool OUTF>
__global__ __launch_bounds__(256, 2) void k_gemm(
        const u16* __restrict__ A, const u16* __restrict__ Bt, void* __restrict__ C,
        size_t c_off, int N, const void* __restrict__ bias,
        const void* __restrict__ res, size_t res_off, int n0,
        const int* __restrict__ flagp) {
    constexpr int K = 256;
    const int flag = *flagp;
    __shared__ u16 sA[128 * 40];
    __shared__ u16 sB[128 * 40];
    const int tid = threadIdx.x;
    const int bm = blockIdx.x * 128, bn = blockIdx.y * 128;
    const int wave = tid >> 6, lane = tid & 63;
    const int wm = (wave >> 1) * 64, wn = (wave & 1) * 64;
    const int lr = lane & 15, lq = lane >> 4;
    f32x4 acc[4][4];
    #pragma unroll
    for (int a = 0; a < 4; a++)
        #pragma unroll
        for (int b2 = 0; b2 < 4; b2++) {
            acc[a][b2][0] = 0.f; acc[a][b2][1] = 0.f;
            acc[a][b2][2] = 0.f; acc[a][b2][3] = 0.f;
        }
    for (int k0 = 0; k0 < K; k0 += 32) {
        for (int c = tid; c < 512; c += 256) {
            int r = c >> 2, cc = (c & 3) << 3;
            *(uint4*)(sA + r * 40 + cc) = *(const uint4*)(A + (size_t)(bm + r) * K + k0 + cc);
            *(uint4*)(sB + r * 40 + cc) = *(const uint4*)(Bt + (size_t)(bn + r) * K + k0 + cc);
        }
        __syncthreads();
        bf16x8 af[4], bfr[4];
        #pragma unroll
        for (int t = 0; t < 4; t++) {
            af[t]  = *(const bf16x8*)(sA + (wm + t * 16 + lr) * 40 + lq * 8);
            bfr[t] = *(const bf16x8*)(sB + (wn + t * 16 + lr) * 40 + lq * 8);
        }
        #pragma unroll
        for (int mt = 0; mt < 4; mt++)
            #pragma unroll
            for (int nt = 0; nt < 4; nt++)
                acc[mt][nt] = __builtin_amdgcn_mfma_f32_16x16x32_bf16(
                        af[mt], bfr[nt], acc[mt][nt], 0, 0, 0);
        __syncthreads();
    }
    #pragma unroll
    for (int mt = 0; mt < 4; mt++)
        #pragma unroll
        for (int nt = 0; nt < 4; nt++)
            #pragma unroll
            for (int r = 0; r < 4; r++) {
                int row = bm + wm + mt * 16 + lq * 4 + r;
                int orow = PERM ? ((row & 127) * 256 + n0 + (row >> 7)) : row;
                int col = bn + wn + nt * 16 + lr;
                float v = acc[mt][nt][r];
                if (EPI) {
                    float bv = flag ? ((const float*)bias)[col] : bf2f(((const u16*)bias)[col]);
                    size_t ri = res_off + (size_t)orow * N + col;
                    float rv = (RESF && flag) ? ((const float*)res)[ri]
                                              : bf2f(((const u16*)res)[ri]);
                    v += bv + rv;
                }
                size_t ci = c_off + (size_t)orow * N + col;
                if (OUTF && flag) ((float*)C)[ci] = v;
                else ((u16*)C)[ci] = f2bf(v);
            }
}

// ---------------- MFMA flash attention (transposed-S) + output gating ----------------
// P: [rows][1024] bf16 = [q|k|v|g]. Block = (head h, group b). Wave owns 64 queries
// (4 tiles of 16). S^T = K·Q^T via MFMA(A=K,B=Q): C col=query, row=key, so each
// query's full key row lives in 4 lq-lanes -> full softmax with only 4 shuffles.
// P (bf16) -> per-wave LDS scratch in A-layout -> O += P·V^T (MFMA). No barriers
// in the main loop: pscr is per-wave (in-order DS + compiler lgkmcnt).
template<bool HB, int L>
__global__ __launch_bounds__(L) void k_attn_mfma(
        const u16* __restrict__ P, const float* __restrict__ bias,
        const int* __restrict__ mask, const void* __restrict__ bg,
        u16* __restrict__ out, int bstride, int mi_s, int mb_s, int m_base,
        const int* __restrict__ flagp) {
    constexpr int WAVES = L / 64;
    constexpr int KT = L / 16;        // key tiles per query row
    constexpr int NCH = L / 32;       // PV chunks (32 keys)
    constexpr int VROW = L + 8;       // svt row stride (16B-aligned, 2-way banks)
    constexpr int PROW = L + 8;       // pscr row stride
    __shared__ u16 sk[L * 40];        // K/sqrt(d) rows [L][32] pad 40
    __shared__ u16 svt[32 * VROW];    // V^T [32][L]
    __shared__ u16 pscr[WAVES * 16 * PROW];  // per-wave P [16 queries][L keys]
    __shared__ float smk[L];
    const int flag = *flagp;
    const int h = blockIdx.x, b = blockIdx.y;
    const int tid = threadIdx.x;
    constexpr float SCALE = 0.17677669529663687f;  // 1/sqrt(32)
    constexpr float LOG2E = 1.4426950408889634f;

    // ---- stage K (pre-scaled), V^T, mask ----
    {
        const size_t prow = (size_t)(b * bstride + tid) * 1024 + h * 32;
        const u16* kp = P + prow + 256;
        #pragma unroll
        for (int c = 0; c < 4; c++) {
            float kf[8];
            unpack8(*(const uint4*)(kp + c * 8), kf);
            uint4 w;
            w.x = (u32)f2bf(kf[0] * SCALE) | ((u32)f2bf(kf[1] * SCALE) << 16);
            w.y = (u32)f2bf(kf[2] * SCALE) | ((u32)f2bf(kf[3] * SCALE) << 16);
            w.z = (u32)f2bf(kf[4] * SCALE) | ((u32)f2bf(kf[5] * SCALE) << 16);
            w.w = (u32)f2bf(kf[6] * SCALE) | ((u32)f2bf(kf[7] * SCALE) << 16);
            *(uint4*)(sk + tid * 40 + c * 8) = w;
        }
        const u16* vp = P + prow + 512;
        #pragma unroll
        for (int c = 0; c < 4; c++) {
            uint4 d = *(const uint4*)(vp + c * 8);
            u16 hw[8];
            hw[0] = (u16)(d.x & 0xffffu); hw[1] = (u16)(d.x >> 16);
            hw[2] = (u16)(d.y & 0xffffu); hw[3] = (u16)(d.y >> 16);
            hw[4] = (u16)(d.z & 0xffffu); hw[5] = (u16)(d.z >> 16);
            hw[6] = (u16)(d.w & 0xffffu); hw[7] = (u16)(d.w >> 16);
            #pragma unroll
            for (int e = 0; e < 8; e++)
                svt[(c * 8 + e) * VROW + tid] = hw[e];
        }
        smk[tid] = (mask[tid * mi_s + b * mb_s + m_base] != 0) ? 1.f : 0.f;
    }
    __syncthreads();

    const int wave = tid >> 6, lane = tid & 63;
    const int lq = lane >> 4, lr = lane & 15;
    const int qbase = wave * 64;
    u16* pw = pscr + wave * 16 * PROW;

    // Q fragments: register layout identical for A and B operands (read [lr][lq*8..+8])
    bf16x8 qf[4];
    #pragma unroll
    for (int qt = 0; qt < 4; qt++) {
        const size_t qrow = (size_t)(b * bstride + qbase + qt * 16 + lr) * 1024 + h * 32;
        qf[qt] = *(const bf16x8*)(P + qrow + lq * 8);
    }
    float bgv[2];
    #pragma unroll
    for (int dt = 0; dt < 2; dt++)
        bgv[dt] = flag ? ((const float*)bg)[h * 32 + dt * 16 + lr]
                       : bf2f(((const u16*)bg)[h * 32 + dt * 16 + lr]);

    const f32x4 zero = {0.f, 0.f, 0.f, 0.f};
    #pragma unroll
    for (int qt = 0; qt < 4; qt++) {
        // ---- S^T: 16(keys) x 16(queries) tiles, col=query=lr, row=key=lq*4+r ----
        f32x4 s[KT];
        #pragma unroll
        for (int kt = 0; kt < KT; kt++) {
            bf16x8 ak = *(const bf16x8*)(sk + (kt * 16 + lr) * 40 + lq * 8);
            s[kt] = __builtin_amdgcn_mfma_f32_16x16x32_bf16(ak, qf[qt], zero, 0, 0, 0);
        }
        // ---- bias + mask + max (in-lane over KT*4 keys, then 2 shuffles) ----
        const float qv = smk[qbase + qt * 16 + lr];
        float mx = -1e9f;
        #pragma unroll
        for (int kt = 0; kt < KT; kt++) {
            const float4 km = *(const float4*)(smk + kt * 16 + lq * 4);
            float4 bv4 = make_float4(0.f, 0.f, 0.f, 0.f);
            if (HB)
                bv4 = *(const float4*)(bias +
                        ((size_t)(h * 256 + qbase + qt * 16 + lr)) * 256 + kt * 16 + lq * 4);
            const float* kmp = (const float*)&km;
            const float* bvp = (const float*)&bv4;
            #pragma unroll
            for (int r = 0; r < 4; r++) {
                float v = s[kt][r] + bvp[r];
                v = (qv > 0.f && kmp[r] > 0.f) ? v : -1e9f;
                s[kt][r] = v;
                mx = fmaxf(mx, v);
            }
        }
        mx = fmaxf(mx, __shfl_xor(mx, 16, 64));
        mx = fmaxf(mx, __shfl_xor(mx, 32, 64));
        // ---- exp, sum, pack P -> per-wave LDS (A-layout [query=lr][key]) ----
        float lsum = 0.f;
        #pragma unroll
        for (int kt = 0; kt < KT; kt++) {
            float p[4];
            #pragma unroll
            for (int r = 0; r < 4; r++) {
                p[r] = exp2f((s[kt][r] - mx) * LOG2E);
                lsum += p[r];
            }
            union { float f; u32 u; } a0, a1, a2, a3;
            a0.f = p[0]; a1.f = p[1]; a2.f = p[2]; a3.f = p[3];
            uint2 wv;
            wv.x = ((a0.u + 0x8000u) >> 16) | (((a1.u + 0x8000u) >> 16) << 16);
            wv.y = ((a2.u + 0x8000u) >> 16) | (((a3.u + 0x8000u) >> 16) << 16);
            *(uint2*)(pw + lr * PROW + kt * 16 + lq * 4) = wv;
        }
        lsum += __shfl_xor(lsum, 16, 64);
        lsum += __shfl_xor(lsum, 32, 64);
        __builtin_amdgcn_wave_barrier();
        // ---- O^C[q][d] += P·V^T over 32-key chunks ----
        f32x4 o0 = zero, o1 = zero;
        #pragma unroll
        for (int c = 0; c < NCH; c++) {
            bf16x8 pa  = *(const bf16x8*)(pw + lr * PROW + c * 32 + lq * 8);
            bf16x8 vb0 = *(const bf16x8*)(svt + (size_t)lr * VROW + c * 32 + lq * 8);
            bf16x8 vb1 = *(const bf16x8*)(svt + (size_t)(16 + lr) * VROW + c * 32 + lq * 8);
            o0 = __builtin_amdgcn_mfma_f32_16x16x32_bf16(pa, vb0, o0, 0, 0, 0);
            o1 = __builtin_amdgcn_mfma_f32_16x16x32_bf16(pa, vb1, o1, 0, 0, 0);
        }
        __builtin_amdgcn_wave_barrier();
        // ---- epilogue: 1/l, gate sigmoid, store (O rows = queries lq*4+r) ----
        #pragma unroll
        for (int r = 0; r < 4; r++) {
            const float lq_l = __shfl(lsum, (lane & 48) | (lq * 4 + r), 64);
            const float inv = 1.f / lq_l;
            const size_t row = (size_t)(b * bstride + qbase + qt * 16 + lq * 4 + r);
            const u16* gp = P + row * 1024 + 768 + h * 32;
            u16* op = out + row * 256 + h * 32;
            #pragma unroll
            for (int dt = 0; dt < 2; dt++) {
                const float ov = (dt ? o1[r] : o0[r]) * inv;
                const float g = bf2f(gp[dt * 16 + lr]) + bgv[dt];
                const float sig = 1.f / (1.f + exp2f(-g * LOG2E));
                op[dt * 16 + lr] = f2bf(ov * sig);
            }
        }
    }
}

extern "C" void kernel_launch(void* const* d_in, const int* in_sizes, int n_in,
                              void* d_out, int out_size, void* d_ws, size_t ws_size,
                              hipStream_t stream) {
    (void)in_sizes; (void)n_in; (void)out_size;
    const void* x        = d_in[0];
    const void* pw       = d_in[1];
    const int*  mask     = (const int*)d_in[2];
    const void* row_ln_g = d_in[3];
    const void* row_ln_b = d_in[4];
    const void* row_wq   = d_in[5];
    const void* row_wkv  = d_in[6];
    const void* row_wg   = d_in[7];
    const void* row_bg   = d_in[8];
    const void* row_wo   = d_in[9];
    const void* row_bo   = d_in[10];
    const void* row_we   = d_in[11];
    const void* col_ln_g = d_in[12];
    const void* col_ln_b = d_in[13];
    const void* col_wq   = d_in[14];
    const void* col_wkv  = d_in[15];
    const void* col_wg   = d_in[16];
    const void* col_bg   = d_in[17];
    const void* col_wo   = d_in[18];
    const void* col_bo   = d_in[19];

    // choose chunking from ws_size (host-side, capture-stable):
    const int nc = (ws_size >= 120193536u) ? 1 : 8;
    const int rows = 32768 / nc;          // rows per chunk

    char* ws = (char*)d_ws;
    size_t off = 0;
    int*   flagp  = (int*)(ws + off);  off += 512;
    u16*   Wt     = (u16*)(ws + off);  off += 524288;      // [1024][256] bf16
    u16*   WoT    = (u16*)(ws + off);  off += 131072;      // [256][256] bf16
    float* biasb  = (float*)(ws + off); off += 2097152;    // [8][256][256] fp32
    u16*   xn_c   = (u16*)(ws + off);  off += (size_t)rows * 512;   // bf16
    u16*   attn_c = (u16*)(ws + off);  off += (size_t)rows * 512;   // bf16
    u16*   P_c    = (u16*)(ws + off);  off += (size_t)rows * 2048;  // bf16
    u16*   x1     = (u16*)(ws + off);  off += 16777216;    // [32768][256] bf16

    k_flag<<<1, 256, 0, stream>>>(x, flagp);

    // ---------------- stage 1: row attention (x1 in ws, bf16) ----------------
    k_tr<<<256, 256, 0, stream>>>(row_wq,  Wt,             256, 256, flagp);
    k_tr<<<512, 256, 0, stream>>>(row_wkv, Wt + 256 * 256, 256, 512, flagp);
    k_tr<<<256, 256, 0, stream>>>(row_wg,  Wt + 768 * 256, 256, 256, flagp);
    k_tr<<<256, 256, 0, stream>>>(row_wo,  WoT,            256, 256, flagp);
    k_bias<<<256, 256, 0, stream>>>(pw, row_we, biasb, flagp);
    for (int c = 0; c < nc; c++) {
        const int s0 = c * (128 / nc);    // first MSA row of chunk
        k_ln<<<rows / 4, 256, 0, stream>>>(x, row_ln_g, row_ln_b, xn_c,
                                           128, 1, s0 * 256, flagp, 1);
        k_gemm<false, false, false, false><<<dim3(rows / 128, 8), 256, 0, stream>>>(
                xn_c, Wt, P_c, 0, 1024, nullptr, nullptr, 0, 0, flagp);
        k_attn_mfma<true, 256><<<dim3(8, 128 / nc), 256, 0, stream>>>(
                P_c, biasb, mask, row_bg, attn_c, 256, 1, 256, s0 * 256, flagp);
        k_gemm<true, false, true, false><<<dim3(rows / 128, 2), 256, 0, stream>>>(
                attn_c, WoT, x1, (size_t)s0 * 65536, 256,
                row_bo, x, (size_t)s0 * 65536, 0, flagp);
    }

    // ---------------- stage 2: column attention (reads x1 bf16, writes d_out) ----------------
    k_tr<<<256, 256, 0, stream>>>(col_wq,  Wt,             256, 256, flagp);
    k_tr<<<512, 256, 0, stream>>>(col_wkv, Wt + 256 * 256, 256, 512, flagp);
    k_tr<<<256, 256, 0, stream>>>(col_wg,  Wt + 768 * 256, 256, 256, flagp);
    k_tr<<<256, 256, 0, stream>>>(col_wo,  WoT,            256, 256, flagp);
    for (int c = 0; c < nc; c++) {
        const int n0 = c * (256 / nc);    // first residue column of chunk
        k_ln<<<rows / 4, 256, 0, stream>>>(x1, col_ln_g, col_ln_b, xn_c,
                                           1, 256, n0, flagp, 0);
        k_gemm<false, false, false, false><<<dim3(rows / 128, 8), 256, 0, stream>>>(
                xn_c, Wt, P_c, 0, 1024, nullptr, nullptr, 0, 0, flagp);
        k_attn_mfma<false, 128><<<dim3(8, 256 / nc), 128, 0, stream>>>(
                P_c, nullptr, mask, col_bg, attn_c, 128, 256, 1, n0, flagp);
        k_gemm<true, true, false, true><<<dim3(rows / 128, 2), 256, 0, stream>>>(
                attn_c, WoT, d_out, 0, 256, col_bo, x1, 0, n0, flagp);
    }
}